// Round 8
// baseline (243.815 us; speedup 1.0000x reference)
//
#include <hip/hip_runtime.h>
#include <math.h>

// Problem constants (from reference setup_inputs)
#define NB     64      // batch
#define N1V    8192    // obj points per batch
#define NV     778     // recon / gt verts
#define NVP    780     // padded to multiple of 4
#define NFACE  1538
#define NZ     64
#define NPAR   61
#define NPRIOR 204
#define PPT    8       // obj points per thread (rec/gt roles)
#define BIAS   0.0625f // 2|a||t| <= 0.06 < BIAS, so biased partials stay >= 0

// target-axis split: two half-ranges [0,392) and [388,780) (overlap is harmless
// for min/argmin: duplicated j gives identical packed values)
#define HALF_T  392
#define HOFF    388
#define PRI_H   104    // prior halves [0,104) and [100,204)
#define PRI_OFF 100

// k_fused roles
#define REC_BLOCKS 512                 // (batch, chunk-of-2048, half)
#define GT_BLOCKS  512
#define CH_BLOCKS  128                 // (batch, dir)
#define NROLE_BLOCKS (REC_BLOCKS + GT_BLOCKS + CH_BLOCKS)   // 1152
#define CMB_BLOCKS 512
#define ROWS (CH_BLOCKS + CMB_BLOCKS)  // 640 partial rows (cham + combine)

// ws float4 layout per batch (BATCH_F4 float4s):
//   [0,780)     gt4   (x,y,z,|t|^2)            pads w=1e30
//   [780,1560)  rec4  (x,y,z,|t|^2+BIAS)       pads w=1e30
//   [1560,1764) pri4  (biased, subset of rec4)
//   [1764,2542) nrm4  (nx,ny,nz,0)
#define BATCH_F4 2544
// float offsets in ws
#define PART_OFF (NB * BATCH_F4 * 4)          // partials[ROWS][8]
#define MU_OFF   (PART_OFF + ROWS * 8)        // rec packed (dist|idx)  [NB*N1V]
#define MG_OFF   (MU_OFF + NB * N1V)          // gt biased dist bits    [NB*N1V]
#define MP_OFF   (MG_OFF + NB * N1V)          // prior biased dist bits [NB*N1V]
#define INIT_BLOCKS 384                       // init 3*524288 uints -> 0xFFFFFFFF

__device__ __constant__ int c_prior[NPRIOR] = {
  697,698,699,700,712,713,714,715,737,738,739,740,741,743,744,745,746,748,749,750,
  753,754,755,756,757,758,759,760,761,762,763,764,765,766,767,768,
  46,47,48,49,164,165,166,167,194,195,223,237,238,280,281,298,301,317,320,323,
  324,325,326,327,328,329,330,331,332,333,340,341,342,343,344,345,346,347,348,349,
  350,351,352,353,354,355,
  356,357,358,359,375,376,386,387,396,397,402,403,413,429,433,434,435,436,437,438,
  439,440,441,442,443,444,452,453,454,455,456,459,460,461,462,463,464,465,466,467,
  468,469,470,471,484,485,486,496,497,506,507,513,514,524,545,546,547,548,549,550,
  551,552,553,555,563,564,565,566,567,570,572,573,574,575,576,577,578,
  580,581,582,583,600,601,602,614,615,624,625,630,631,641,663,664,665,666,667,668,
  670,672,680,681,682,683,684,686,687,688,689,690,691,692,693,694,695,
  73,96,98,99,772,774,775,777
};

// ---------------- Kernel 0: per-batch target arrays + normals + minima init ---
__global__ __launch_bounds__(256) void k_prep(const float* __restrict__ recon,
                                              const float* __restrict__ gt,
                                              const int* __restrict__ faces,
                                              float4* __restrict__ ws4,
                                              unsigned int* __restrict__ mins) {
    int tid = threadIdx.x;
    if (blockIdx.x >= NB) {
        // init the 3 atomic-min arrays to 0xFFFFFFFF (16 uints/thread)
        unsigned int* p = mins + (size_t)(blockIdx.x - NB) * 4096 + tid * 4;
#pragma unroll
        for (int k = 0; k < 4; ++k) {
            *(uint4*)(p + (size_t)k * 1024) =
                make_uint4(0xFFFFFFFFu, 0xFFFFFFFFu, 0xFFFFFFFFu, 0xFFFFFFFFu);
        }
        return;
    }
    int b = blockIdx.x;
    __shared__ float4 s_r[NV];
    __shared__ float s_vnx[NV], s_vny[NV], s_vnz[NV];
    const float* rb = recon + (size_t)b * NV * 3;
    const float* gb = gt    + (size_t)b * NV * 3;
    float4* gt4  = ws4 + (size_t)b * BATCH_F4;
    float4* rec4 = gt4 + NVP;
    float4* pri4 = rec4 + NVP;
    float4* nrm4 = pri4 + NPRIOR;
    for (int j = tid; j < NVP; j += 256) {
        if (j < NV) {
            float x = rb[3*j], y = rb[3*j+1], z = rb[3*j+2];
            float4 r = make_float4(x, y, z, x*x + y*y + z*z + BIAS);
            s_r[j] = r; rec4[j] = r;
            x = gb[3*j]; y = gb[3*j+1]; z = gb[3*j+2];
            gt4[j] = make_float4(x, y, z, x*x + y*y + z*z);
            s_vnx[j] = 0.0f; s_vny[j] = 0.0f; s_vnz[j] = 0.0f;
        } else {
            float4 pad = make_float4(0.f, 0.f, 0.f, 1e30f);
            rec4[j] = pad; gt4[j] = pad;
        }
    }
    __syncthreads();
    for (int f = tid; f < NFACE; f += 256) {
        int i0 = faces[3*f], i1 = faces[3*f+1], i2 = faces[3*f+2];
        float4 p0 = s_r[i0], p1 = s_r[i1], p2 = s_r[i2];
        float e1x = p1.x - p0.x, e1y = p1.y - p0.y, e1z = p1.z - p0.z;
        float e2x = p2.x - p0.x, e2y = p2.y - p0.y, e2z = p2.z - p0.z;
        float fx = e1y * e2z - e1z * e2y;
        float fy = e1z * e2x - e1x * e2z;
        float fz = e1x * e2y - e1y * e2x;
        atomicAdd(&s_vnx[i0], fx); atomicAdd(&s_vny[i0], fy); atomicAdd(&s_vnz[i0], fz);
        atomicAdd(&s_vnx[i1], fx); atomicAdd(&s_vny[i1], fy); atomicAdd(&s_vnz[i1], fz);
        atomicAdd(&s_vnx[i2], fx); atomicAdd(&s_vny[i2], fy); atomicAdd(&s_vnz[i2], fz);
    }
    __syncthreads();
    for (int j = tid; j < NV; j += 256) {
        float x = s_vnx[j], y = s_vny[j], z = s_vnz[j];
        float inv = 1.0f / (sqrtf(x*x + y*y + z*z) + 1e-12f);
        nrm4[j] = make_float4(x * inv, y * inv, z * inv, 0.0f);
    }
    for (int k = tid; k < NPRIOR; k += 256) pri4[k] = s_r[c_prior[k]];
}

// ---------------- Fused role kernel ----------------
// [0,512): rec half-target argmin + prior half  [512,1024): gt half-target min
// [1024,1152): chamfer
__global__ __launch_bounds__(256) void k_fused(const float* __restrict__ obj,
                                               const float4* __restrict__ ws4,
                                               float* __restrict__ part,
                                               unsigned int* __restrict__ mu_arr,
                                               unsigned int* __restrict__ mg_arr,
                                               unsigned int* __restrict__ mp_arr) {
    __shared__ float4 s_t[NVP];
    __shared__ float4 s_p[PRI_H];
    __shared__ float s_red[1];
    int tid = threadIdx.x;
    int blk = blockIdx.x;

    if (blk < REC_BLOCKS) {
        // ============ REC(half) + PRIOR(half) ROLE ============
        int b = blk >> 3, chunk = (blk >> 1) & 3, h = blk & 1;
        int hoff = h * HOFF, poff = h * PRI_OFF;
        const float4* base = ws4 + (size_t)b * BATCH_F4;
        const float4* rec4v = base + NVP + hoff;
        const float4* pri4v = base + 2 * NVP + poff;
        for (int j = tid; j < HALF_T; j += 256) s_t[j] = rec4v[j];
        for (int k = tid; k < PRI_H; k += 256) s_p[k] = pri4v[k];
        __syncthreads();

        const float* ob = obj + ((size_t)b * N1V + (size_t)chunk * 2048) * 3;
        const float4* ob4 = (const float4*)(ob + (size_t)tid * 24);
        float4 q0 = ob4[0], q1 = ob4[1], q2 = ob4[2], q3 = ob4[3], q4 = ob4[4], q5 = ob4[5];

        float nax[PPT], nay[PPT], naz[PPT], mpri[PPT];
        unsigned int mu[PPT];
        {
            float px[PPT], py[PPT], pz[PPT];
            px[0]=q0.x; py[0]=q0.y; pz[0]=q0.z;
            px[1]=q0.w; py[1]=q1.x; pz[1]=q1.y;
            px[2]=q1.z; py[2]=q1.w; pz[2]=q2.x;
            px[3]=q2.y; py[3]=q2.z; pz[3]=q2.w;
            px[4]=q3.x; py[4]=q3.y; pz[4]=q3.z;
            px[5]=q3.w; py[5]=q4.x; pz[5]=q4.y;
            px[6]=q4.z; py[6]=q4.w; pz[6]=q5.x;
            px[7]=q5.y; py[7]=q5.z; pz[7]=q5.w;
#pragma unroll
            for (int i = 0; i < PPT; ++i) {
                nax[i] = -2.0f * px[i]; nay[i] = -2.0f * py[i]; naz[i] = -2.0f * pz[i];
                mpri[i] = 3.4e38f; mu[i] = 0xFFFFFFFFu;
            }
        }
        // rec half-stream: packed (dist|idx) uint-min argmin (biased d >= 0)
        for (int j = 0; j < HALF_T; j += 4) {
            float4 t0 = s_t[j], t1 = s_t[j+1], t2 = s_t[j+2], t3 = s_t[j+3];
            unsigned int jj = (unsigned int)(hoff + j);
#pragma unroll
            for (int i = 0; i < PPT; ++i) {
                float d0 = fmaf(nax[i], t0.x, fmaf(nay[i], t0.y, fmaf(naz[i], t0.z, t0.w)));
                float d1 = fmaf(nax[i], t1.x, fmaf(nay[i], t1.y, fmaf(naz[i], t1.z, t1.w)));
                float d2 = fmaf(nax[i], t2.x, fmaf(nay[i], t2.y, fmaf(naz[i], t2.z, t2.w)));
                float d3 = fmaf(nax[i], t3.x, fmaf(nay[i], t3.y, fmaf(naz[i], t3.z, t3.w)));
                unsigned int u0 = (__float_as_uint(d0) & 0xFFFFFC00u) | jj;
                unsigned int u1 = (__float_as_uint(d1) & 0xFFFFFC00u) | (jj+1u);
                unsigned int u2 = (__float_as_uint(d2) & 0xFFFFFC00u) | (jj+2u);
                unsigned int u3 = (__float_as_uint(d3) & 0xFFFFFC00u) | (jj+3u);
                mu[i] = min(min(mu[i], u0), min(min(u1, u2), u3));
            }
        }
        // prior half-stream (biased values, plain min)
        for (int j = 0; j < PRI_H; j += 4) {
            float4 t0 = s_p[j], t1 = s_p[j+1], t2 = s_p[j+2], t3 = s_p[j+3];
#pragma unroll
            for (int i = 0; i < PPT; ++i) {
                float d0 = fmaf(nax[i], t0.x, fmaf(nay[i], t0.y, fmaf(naz[i], t0.z, t0.w)));
                float d1 = fmaf(nax[i], t1.x, fmaf(nay[i], t1.y, fmaf(naz[i], t1.z, t1.w)));
                float d2 = fmaf(nax[i], t2.x, fmaf(nay[i], t2.y, fmaf(naz[i], t2.z, t2.w)));
                float d3 = fmaf(nax[i], t3.x, fmaf(nay[i], t3.y, fmaf(naz[i], t3.z, t3.w)));
                mpri[i] = fminf(fminf(mpri[i], d0), fminf(d2, fminf(d1, d3)));
            }
        }
        int pbase = b * N1V + chunk * 2048 + tid * PPT;
#pragma unroll
        for (int i = 0; i < PPT; ++i) {
            atomicMin(&mu_arr[pbase + i], mu[i]);
            atomicMin(&mp_arr[pbase + i], __float_as_uint(mpri[i]));
        }
        return;
    }

    if (blk < REC_BLOCKS + GT_BLOCKS) {
        // ============ GT(half) ROLE ============
        int r = blk - REC_BLOCKS;
        int b = r >> 3, chunk = (r >> 1) & 3, h = r & 1;
        int hoff = h * HOFF;
        const float4* gt4v = ws4 + (size_t)b * BATCH_F4 + hoff;
        for (int j = tid; j < HALF_T; j += 256) s_t[j] = gt4v[j];
        __syncthreads();

        const float* ob = obj + ((size_t)b * N1V + (size_t)chunk * 2048) * 3;
        const float4* ob4 = (const float4*)(ob + (size_t)tid * 24);
        float4 q0 = ob4[0], q1 = ob4[1], q2 = ob4[2], q3 = ob4[3], q4 = ob4[4], q5 = ob4[5];

        float nax[PPT], nay[PPT], naz[PPT], mgt[PPT];
        {
            float px[PPT], py[PPT], pz[PPT];
            px[0]=q0.x; py[0]=q0.y; pz[0]=q0.z;
            px[1]=q0.w; py[1]=q1.x; pz[1]=q1.y;
            px[2]=q1.z; py[2]=q1.w; pz[2]=q2.x;
            px[3]=q2.y; py[3]=q2.z; pz[3]=q2.w;
            px[4]=q3.x; py[4]=q3.y; pz[4]=q3.z;
            px[5]=q3.w; py[5]=q4.x; pz[5]=q4.y;
            px[6]=q4.z; py[6]=q4.w; pz[6]=q5.x;
            px[7]=q5.y; py[7]=q5.z; pz[7]=q5.w;
#pragma unroll
            for (int i = 0; i < PPT; ++i) {
                nax[i] = -2.0f * px[i]; nay[i] = -2.0f * py[i]; naz[i] = -2.0f * pz[i];
                mgt[i] = 3.4e38f;
            }
        }
        for (int j = 0; j < HALF_T; j += 4) {
            float4 t0 = s_t[j], t1 = s_t[j+1], t2 = s_t[j+2], t3 = s_t[j+3];
#pragma unroll
            for (int i = 0; i < PPT; ++i) {
                float d0 = fmaf(nax[i], t0.x, fmaf(nay[i], t0.y, fmaf(naz[i], t0.z, t0.w)));
                float d1 = fmaf(nax[i], t1.x, fmaf(nay[i], t1.y, fmaf(naz[i], t1.z, t1.w)));
                float d2 = fmaf(nax[i], t2.x, fmaf(nay[i], t2.y, fmaf(naz[i], t2.z, t2.w)));
                float d3 = fmaf(nax[i], t3.x, fmaf(nay[i], t3.y, fmaf(naz[i], t3.z, t3.w)));
                mgt[i] = fminf(fminf(mgt[i], d0), fminf(d2, fminf(d1, d3)));
            }
        }
        int pbase = b * N1V + chunk * 2048 + tid * PPT;
#pragma unroll
        for (int i = 0; i < PPT; ++i)
            atomicMin(&mg_arr[pbase + i], __float_as_uint(mgt[i] + BIAS));
        return;
    }

    // ============ CHAMFER ROLE (full targets, 4 src/thread) ============
    {
        int c   = blk - (REC_BLOCKS + GT_BLOCKS);
        int b   = c >> 1;
        int dir = c & 1;           // 0: rec->gt, 1: gt->rec
        const float4* base = ws4 + (size_t)b * BATCH_F4;
        const float4* srcv = dir ? base : (base + NVP);   // gt4 : rec4
        const float4* tgtv = dir ? (base + NVP) : base;   // rec4 : gt4
        for (int j = tid; j < NVP; j += 256) s_t[j] = tgtv[j];
        if (tid == 0) s_red[0] = 0.0f;
        __syncthreads();

        const int CPT = 4;               // 256*4 = 1024 >= 778 sources
        float nax[CPT], nay[CPT], naz[CPT], a2[CPT], m[CPT];
        bool valid[CPT];
#pragma unroll
        for (int k = 0; k < CPT; ++k) {
            int p = tid + 256 * k;
            valid[k] = (p < NV);
            float4 s = srcv[valid[k] ? p : 0];
            nax[k] = -2.0f * s.x; nay[k] = -2.0f * s.y; naz[k] = -2.0f * s.z;
            a2[k] = s.w;                  // one of src/tgt carries +BIAS
            m[k] = 3.4e38f;
        }
        for (int j = 0; j < NVP; j += 4) {
            float4 t0 = s_t[j], t1 = s_t[j+1], t2 = s_t[j+2], t3 = s_t[j+3];
#pragma unroll
            for (int k = 0; k < CPT; ++k) {
                float d0 = fmaf(nax[k], t0.x, fmaf(nay[k], t0.y, fmaf(naz[k], t0.z, t0.w)));
                float d1 = fmaf(nax[k], t1.x, fmaf(nay[k], t1.y, fmaf(naz[k], t1.z, t1.w)));
                float d2 = fmaf(nax[k], t2.x, fmaf(nay[k], t2.y, fmaf(naz[k], t2.z, t2.w)));
                float d3 = fmaf(nax[k], t3.x, fmaf(nay[k], t3.y, fmaf(naz[k], t3.z, t3.w)));
                m[k] = fminf(fminf(m[k], d0), fminf(d2, fminf(d1, d3)));
            }
        }
        float local = 0.0f;
#pragma unroll
        for (int k = 0; k < CPT; ++k)
            if (valid[k]) local += fmaxf(a2[k] + m[k] - BIAS, 0.0f);
        atomicAdd(&s_red[0], local);
        __syncthreads();
        if (tid < 8) {
            float v = (tid == 2) ? s_red[0] : 0.0f;
            part[(size_t)c * 8 + tid] = v;
        }
    }
}

// ---------------- Combine: all per-point epilogue terms ----------------
__global__ __launch_bounds__(256) void k_combine(const float* __restrict__ obj,
                                                 const float4* __restrict__ ws4,
                                                 const unsigned int* __restrict__ mu_arr,
                                                 const unsigned int* __restrict__ mg_arr,
                                                 const unsigned int* __restrict__ mp_arr,
                                                 float* __restrict__ part) {
    int blk = blockIdx.x, tid = threadIdx.x;
    __shared__ float s_red[5];
    if (tid < 5) s_red[tid] = 0.0f;
    __syncthreads();
    int p0 = blk * 1024 + tid * 4;          // 4 consecutive points
    int b  = blk >> 3;
    const float4* base  = ws4 + (size_t)b * BATCH_F4;
    const float4* rec4v = base + NVP;
    const float4* nrm4v = base + 2 * NVP + NPRIOR;

    const float4* ob4 = (const float4*)(obj + (size_t)p0 * 3);
    float4 q0 = ob4[0], q1 = ob4[1], q2 = ob4[2];
    float px[4], py[4], pz[4];
    px[0]=q0.x; py[0]=q0.y; pz[0]=q0.z;
    px[1]=q0.w; py[1]=q1.x; pz[1]=q1.y;
    px[2]=q1.z; py[2]=q1.w; pz[2]=q2.x;
    px[3]=q2.y; py[3]=q2.z; pz[3]=q2.w;
    uint4 mu4 = *(const uint4*)(mu_arr + p0);
    uint4 mg4 = *(const uint4*)(mg_arr + p0);
    uint4 mp4 = *(const uint4*)(mp_arr + p0);
    unsigned int mus[4] = {mu4.x, mu4.y, mu4.z, mu4.w};
    unsigned int mgs[4] = {mg4.x, mg4.y, mg4.z, mg4.w};
    unsigned int mps[4] = {mp4.x, mp4.y, mp4.z, mp4.w};

    float lS_cmap = 0.0f, lN_cmap = 0.0f, lN_gt = 0.0f, lN_cons = 0.0f, lS_pen = 0.0f;
#pragma unroll
    for (int i = 0; i < 4; ++i) {
        float a2 = px[i]*px[i] + py[i]*py[i] + pz[i]*pz[i];
        int j = (int)(mus[i] & 0x3FFu);
        float4 t  = rec4v[j];
        float4 nr = nrm4v[j];
        float dot = fmaf(-2.0f*px[i], t.x, fmaf(-2.0f*py[i], t.y,
                     fmaf(-2.0f*pz[i], t.z, t.w - BIAS)));
        float drec = fmaxf(a2 + dot, 0.0f);
        float dgt  = fmaxf(a2 + (__uint_as_float(mgs[i]) - BIAS), 0.0f);
        float dpri = fmaxf(a2 + (__uint_as_float(mps[i]) - BIAS), 0.0f);
        bool cm = drec < 1e-4f;
        bool rc = sqrtf(drec) < 0.005f;
        bool gc = sqrtf(dgt)  < 0.005f;
        if (cm) { lS_cmap += dpri; lN_cmap += 1.0f; }
        if (gc) { lN_gt += 1.0f; if (rc) lN_cons += 1.0f; }
        float ddot = (t.x - px[i]) * nr.x + (t.y - py[i]) * nr.y + (t.z - pz[i]) * nr.z;
        if (ddot > 0.0f) lS_pen += drec;
    }
    atomicAdd(&s_red[0], lS_cmap);
    atomicAdd(&s_red[1], lN_cmap);
    atomicAdd(&s_red[2], lN_gt);
    atomicAdd(&s_red[3], lN_cons);
    atomicAdd(&s_red[4], lS_pen);
    __syncthreads();
    if (tid < 8) {
        float v = (tid >= 3) ? s_red[tid - 3] : 0.0f;
        part[(size_t)(CH_BLOCKS + blk) * 8 + tid] = v;
    }
}

// ---------------- Finalize: param/KLD reductions + partial row-sum + loss ----
__global__ __launch_bounds__(256) void k_final(const float* __restrict__ part,
                                               const float* __restrict__ mean,
                                               const float* __restrict__ log_var,
                                               const float* __restrict__ rp,
                                               const float* __restrict__ xp,
                                               float* __restrict__ out) {
    int tid = threadIdx.x;
    __shared__ float red[8];
    if (tid < 8) red[tid] = 0.0f;
    __syncthreads();
    float l2=0, l3=0, l4=0, l5=0, l6=0, l7=0;
    for (int r = tid; r < ROWS; r += 256) {
        const float* row = part + (size_t)r * 8;
        l2 += row[2]; l3 += row[3]; l4 += row[4];
        l5 += row[5]; l6 += row[6]; l7 += row[7];
    }
    float s_param = 0.0f, s_kld = 0.0f;
    for (int i = tid; i < NB * NPAR; i += 256) {
        float d = rp[i] - xp[i];
        s_param += d * d;
    }
    for (int i = tid; i < NB * NZ; i += 256) {
        float m = mean[i], lv = log_var[i];
        s_kld += 1.0f + lv - m * m - expf(lv);
    }
    atomicAdd(&red[0], s_param);
    atomicAdd(&red[1], s_kld);
    atomicAdd(&red[2], l2);
    atomicAdd(&red[3], l3);
    atomicAdd(&red[4], l4);
    atomicAdd(&red[5], l5);
    atomicAdd(&red[6], l6);
    atomicAdd(&red[7], l7);
    __syncthreads();
    if (tid == 0) {
        const float fB = 64.0f;
        float param_loss  = red[0] / fB;
        float KLD         = -0.5f * red[1] / fB * 10.0f;
        float recon_loss  = red[2] / fB;
        float cmap_loss   = 3000.0f * red[3] / (fB * red[4]);
        float consistency = -5.0f * red[6] / (red[5] + 0.0001f);
        float penetr      = 100.0f * red[7] / fB;
        out[0] = (recon_loss + KLD) + 0.1f * param_loss + 1000.0f * cmap_loss
               + 10.0f * consistency + 10.0f * penetr;
    }
}

extern "C" void kernel_launch(void* const* d_in, const int* in_sizes, int n_in,
                              void* d_out, int out_size, void* d_ws, size_t ws_size,
                              hipStream_t stream) {
    (void)in_sizes; (void)n_in; (void)out_size; (void)ws_size;
    const float* obj     = (const float*)d_in[0];
    const float* recon   = (const float*)d_in[1];
    const float* gt      = (const float*)d_in[2];
    const float* mean    = (const float*)d_in[3];
    const float* log_var = (const float*)d_in[4];
    const float* rp      = (const float*)d_in[5];
    const float* xp      = (const float*)d_in[6];
    const int*   faces   = (const int*)d_in[7];
    float4* ws4 = (float4*)d_ws;
    float* part = (float*)d_ws + PART_OFF;
    unsigned int* mu = (unsigned int*)((float*)d_ws + MU_OFF);
    unsigned int* mg = (unsigned int*)((float*)d_ws + MG_OFF);
    unsigned int* mp = (unsigned int*)((float*)d_ws + MP_OFF);
    float* out  = (float*)d_out;

    k_prep   <<<NB + INIT_BLOCKS, 256, 0, stream>>>(recon, gt, faces, ws4, mu);
    k_fused  <<<NROLE_BLOCKS,     256, 0, stream>>>(obj, ws4, part, mu, mg, mp);
    k_combine<<<CMB_BLOCKS,       256, 0, stream>>>(obj, ws4, mu, mg, mp, part);
    k_final  <<<1,                256, 0, stream>>>(part, mean, log_var, rp, xp, out);
}

// Round 9
// 224.002 us; speedup vs baseline: 1.0884x; 1.0884x over previous
//
#include <hip/hip_runtime.h>
#include <math.h>

// Problem constants (from reference setup_inputs)
#define NB     64      // batch
#define N1V    8192    // obj points per batch
#define NV     778     // recon / gt verts
#define NVP    780     // padded to multiple of 4
#define NQ     (NVP/4)     // 195 target quads
#define NFACE  1538
#define NZ     64
#define NPAR   61
#define NPRIOR 204
#define NPQ    (NPRIOR/4)  // 51 prior quads
#define PPT    8       // obj points per thread (rec/gt roles)
#define BIAS   0.0625f // 2|a||t| <= 0.06 < BIAS -> biased partials stay >= 0

// k_fused roles
#define REC_BLOCKS 256                 // (batch, chunk-of-2048): rec + prior
#define GT_BLOCKS  256                 // (batch, chunk-of-2048): gt
#define CH_BLOCKS  128                 // (batch, dir): chamfer, 4 src/thread
#define NROLE_BLOCKS (REC_BLOCKS + GT_BLOCKS + CH_BLOCKS)   // 640
#define CMB_BLOCKS 256
#define TOT_ROWS   (NROLE_BLOCKS + CMB_BLOCKS)              // 896

// ws float4 layout per batch (BATCH_F4 float4s):
//   [0,780)     gt4   (x,y,z,|t|^2)            pads w=1e30
//   [780,1560)  rec4  (x,y,z,|t|^2+BIAS)       pads w=1e30
//   [1560,1764) pri4  (biased, subset of rec4)
//   [1764,2542) nrm4  (nx,ny,nz,0)
#define BATCH_F4 2544
// float offsets in ws
#define PART_OFF (NB * BATCH_F4 * 4)          // partials[TOT_ROWS][8]
#define DREC_OFF (PART_OFF + TOT_ROWS * 8)    // drec[NB*N1V]
#define GC_OFF   (DREC_OFF + NB * N1V)        // gc bitmasks, 1 uint / 8 points

// packed fp32: <2 x float> fma -> v_pk_fma_f32 on gfx950 (gfx90a+)
typedef float v2f __attribute__((ext_vector_type(2)));
typedef float v4f __attribute__((ext_vector_type(4)));
#if __has_builtin(__builtin_elementwise_fma)
#define PKFMA(a, b, c) __builtin_elementwise_fma((a), (b), (c))
#else
__device__ __forceinline__ v2f PKFMA(v2f a, v2f b, v2f c) {
    v2f r; r.x = fmaf(a.x, b.x, c.x); r.y = fmaf(a.y, b.y, c.y); return r;
}
#endif
#define LO2(v) __builtin_shufflevector((v), (v), 0, 1)
#define HI2(v) __builtin_shufflevector((v), (v), 2, 3)

__device__ __constant__ int c_prior[NPRIOR] = {
  697,698,699,700,712,713,714,715,737,738,739,740,741,743,744,745,746,748,749,750,
  753,754,755,756,757,758,759,760,761,762,763,764,765,766,767,768,
  46,47,48,49,164,165,166,167,194,195,223,237,238,280,281,298,301,317,320,323,
  324,325,326,327,328,329,330,331,332,333,340,341,342,343,344,345,346,347,348,349,
  350,351,352,353,354,355,
  356,357,358,359,375,376,386,387,396,397,402,403,413,429,433,434,435,436,437,438,
  439,440,441,442,443,444,452,453,454,455,456,459,460,461,462,463,464,465,466,467,
  468,469,470,471,484,485,486,496,497,506,507,513,514,524,545,546,547,548,549,550,
  551,552,553,555,563,564,565,566,567,570,572,573,574,575,576,577,578,
  580,581,583,600,601,602,614,615,624,625,630,631,641,663,664,665,666,667,668,
  670,672,680,681,682,683,684,686,687,688,689,690,691,692,693,694,695,
  73,96,98,99,772,774,775,777,582
};
// NOTE: list above must contain exactly the reference indices; order within the
// constant doesn't matter for min-reductions EXCEPT it must be the same SET.
// (582 moved to the end to keep the initializer intact — set identical.)

// ---------------- Kernel 0: per-batch target arrays + normals ----------------
__global__ __launch_bounds__(256) void k_prep(const float* __restrict__ recon,
                                              const float* __restrict__ gt,
                                              const int* __restrict__ faces,
                                              float4* __restrict__ ws4) {
    int b = blockIdx.x, tid = threadIdx.x;
    __shared__ float4 s_r[NV];
    __shared__ float s_vnx[NV], s_vny[NV], s_vnz[NV];
    const float* rb = recon + (size_t)b * NV * 3;
    const float* gb = gt    + (size_t)b * NV * 3;
    float4* gt4  = ws4 + (size_t)b * BATCH_F4;
    float4* rec4 = gt4 + NVP;
    float4* pri4 = rec4 + NVP;
    float4* nrm4 = pri4 + NPRIOR;
    for (int j = tid; j < NVP; j += 256) {
        if (j < NV) {
            float x = rb[3*j], y = rb[3*j+1], z = rb[3*j+2];
            float4 r = make_float4(x, y, z, x*x + y*y + z*z + BIAS);
            s_r[j] = r; rec4[j] = r;
            x = gb[3*j]; y = gb[3*j+1]; z = gb[3*j+2];
            gt4[j] = make_float4(x, y, z, x*x + y*y + z*z);
            s_vnx[j] = 0.0f; s_vny[j] = 0.0f; s_vnz[j] = 0.0f;
        } else {
            float4 pad = make_float4(0.f, 0.f, 0.f, 1e30f);
            rec4[j] = pad; gt4[j] = pad;
        }
    }
    __syncthreads();
    for (int f = tid; f < NFACE; f += 256) {
        int i0 = faces[3*f], i1 = faces[3*f+1], i2 = faces[3*f+2];
        float4 p0 = s_r[i0], p1 = s_r[i1], p2 = s_r[i2];
        float e1x = p1.x - p0.x, e1y = p1.y - p0.y, e1z = p1.z - p0.z;
        float e2x = p2.x - p0.x, e2y = p2.y - p0.y, e2z = p2.z - p0.z;
        float fx = e1y * e2z - e1z * e2y;
        float fy = e1z * e2x - e1x * e2z;
        float fz = e1x * e2y - e1y * e2x;
        atomicAdd(&s_vnx[i0], fx); atomicAdd(&s_vny[i0], fy); atomicAdd(&s_vnz[i0], fz);
        atomicAdd(&s_vnx[i1], fx); atomicAdd(&s_vny[i1], fy); atomicAdd(&s_vnz[i1], fz);
        atomicAdd(&s_vnx[i2], fx); atomicAdd(&s_vny[i2], fy); atomicAdd(&s_vnz[i2], fz);
    }
    __syncthreads();
    for (int j = tid; j < NV; j += 256) {
        float x = s_vnx[j], y = s_vny[j], z = s_vnz[j];
        float inv = 1.0f / (sqrtf(x*x + y*y + z*z) + 1e-12f);
        nrm4[j] = make_float4(x * inv, y * inv, z * inv, 0.0f);
    }
    for (int k = tid; k < NPRIOR; k += 256) pri4[k] = s_r[c_prior[k]];
}

// transpose-stage 4 consecutive float4 targets into SoA quads
#define STAGE_SOA(dst_x, dst_y, dst_z, dst_w, srcp, n)                      \
    for (int j = tid; j < (n); j += 256) {                                  \
        float4 t0 = (srcp)[4*j], t1 = (srcp)[4*j+1],                        \
               t2 = (srcp)[4*j+2], t3 = (srcp)[4*j+3];                      \
        dst_x[j] = (v4f){t0.x, t1.x, t2.x, t3.x};                           \
        dst_y[j] = (v4f){t0.y, t1.y, t2.y, t3.y};                           \
        dst_z[j] = (v4f){t0.z, t1.z, t2.z, t3.z};                           \
        dst_w[j] = (v4f){t0.w, t1.w, t2.w, t3.w};                           \
    }

// ---------------- Fused role kernel ----------------
// [0,256): rec+prior KNN   [256,512): gt KNN   [512,640): chamfer
__global__ __launch_bounds__(256) void k_fused(const float* __restrict__ obj,
                                               const float4* __restrict__ ws4,
                                               float* __restrict__ part,
                                               float* __restrict__ drec_arr,
                                               unsigned int* __restrict__ gc_arr) {
    __shared__ v4f s_x[NQ], s_y[NQ], s_z[NQ], s_w[NQ];
    __shared__ v4f s_px[NPQ], s_py[NPQ], s_pz[NPQ], s_pw[NPQ];
    __shared__ float s_red[4];
    int tid = threadIdx.x;
    int blk = blockIdx.x;

    if (blk < REC_BLOCKS) {
        // ============ REC + PRIOR ROLE (PPT=8, packed fp32) ============
        int b = blk >> 2, chunk = blk & 3;
        const float4* base = ws4 + (size_t)b * BATCH_F4;
        const float4* rec4v = base + NVP;
        const float4* pri4v = base + 2 * NVP;
        const float4* nrm4v = pri4v + NPRIOR;
        STAGE_SOA(s_x, s_y, s_z, s_w, rec4v, NQ)
        STAGE_SOA(s_px, s_py, s_pz, s_pw, pri4v, NPQ)
        if (tid < 4) s_red[tid] = 0.0f;
        __syncthreads();

        const float* ob = obj + ((size_t)b * N1V + (size_t)chunk * 2048) * 3;
        const float4* ob4 = (const float4*)(ob + (size_t)tid * 24);
        float4 q0 = ob4[0], q1 = ob4[1], q2 = ob4[2], q3 = ob4[3], q4 = ob4[4], q5 = ob4[5];

        v2f nax2[PPT], nay2[PPT], naz2[PPT];
        float mpri[PPT];
        unsigned int mu[PPT];
        {
            float px[PPT], py[PPT], pz[PPT];
            px[0]=q0.x; py[0]=q0.y; pz[0]=q0.z;
            px[1]=q0.w; py[1]=q1.x; pz[1]=q1.y;
            px[2]=q1.z; py[2]=q1.w; pz[2]=q2.x;
            px[3]=q2.y; py[3]=q2.z; pz[3]=q2.w;
            px[4]=q3.x; py[4]=q3.y; pz[4]=q3.z;
            px[5]=q3.w; py[5]=q4.x; pz[5]=q4.y;
            px[6]=q4.z; py[6]=q4.w; pz[6]=q5.x;
            px[7]=q5.y; py[7]=q5.z; pz[7]=q5.w;
#pragma unroll
            for (int i = 0; i < PPT; ++i) {
                float ax = -2.0f * px[i], ay = -2.0f * py[i], az = -2.0f * pz[i];
                nax2[i] = (v2f){ax, ax}; nay2[i] = (v2f){ay, ay}; naz2[i] = (v2f){az, az};
                mpri[i] = 3.4e38f; mu[i] = 0xFFFFFFFFu;
            }
        }
        // rec stream: packed distances, (dist|idx) uint-min argmin (biased d>=0)
        for (int j = 0; j < NQ; ++j) {
            v4f x4 = s_x[j], y4 = s_y[j], z4 = s_z[j], w4 = s_w[j];
            v2f xa = LO2(x4), xb = HI2(x4), ya = LO2(y4), yb = HI2(y4);
            v2f za = LO2(z4), zb = HI2(z4), wa = LO2(w4), wb = HI2(w4);
            unsigned int jj = (unsigned int)(4 * j);
#pragma unroll
            for (int i = 0; i < PPT; ++i) {
                v2f da = PKFMA(nax2[i], xa, PKFMA(nay2[i], ya, PKFMA(naz2[i], za, wa)));
                v2f db = PKFMA(nax2[i], xb, PKFMA(nay2[i], yb, PKFMA(naz2[i], zb, wb)));
                unsigned int u0 = (__float_as_uint(da.x) & 0xFFFFFC00u) | jj;
                unsigned int u1 = (__float_as_uint(da.y) & 0xFFFFFC00u) | (jj+1u);
                unsigned int u2 = (__float_as_uint(db.x) & 0xFFFFFC00u) | (jj+2u);
                unsigned int u3 = (__float_as_uint(db.y) & 0xFFFFFC00u) | (jj+3u);
                mu[i] = min(min(mu[i], min(u0, u1)), min(u2, u3));
            }
        }
        // prior stream (biased values, plain min)
        for (int j = 0; j < NPQ; ++j) {
            v4f x4 = s_px[j], y4 = s_py[j], z4 = s_pz[j], w4 = s_pw[j];
            v2f xa = LO2(x4), xb = HI2(x4), ya = LO2(y4), yb = HI2(y4);
            v2f za = LO2(z4), zb = HI2(z4), wa = LO2(w4), wb = HI2(w4);
#pragma unroll
            for (int i = 0; i < PPT; ++i) {
                v2f da = PKFMA(nax2[i], xa, PKFMA(nay2[i], ya, PKFMA(naz2[i], za, wa)));
                v2f db = PKFMA(nax2[i], xb, PKFMA(nay2[i], yb, PKFMA(naz2[i], zb, wb)));
                mpri[i] = fminf(fminf(mpri[i], fminf(da.x, da.y)), fminf(db.x, db.y));
            }
        }
        const float* fx = (const float*)s_x;
        const float* fy = (const float*)s_y;
        const float* fz = (const float*)s_z;
        const float* fw = (const float*)s_w;
        float lS_cmap = 0.0f, lN_cmap = 0.0f, lS_pen = 0.0f;
        float dr[PPT];
#pragma unroll
        for (int i = 0; i < PPT; ++i) {
            float ax = -0.5f * nax2[i].x, ay = -0.5f * nay2[i].x, az = -0.5f * naz2[i].x;
            float a2 = ax*ax + ay*ay + az*az;
            float dpri = fmaxf(a2 + (mpri[i] - BIAS), 0.0f);
            int j = (int)(mu[i] & 0x3FFu);
            float tx = fx[j], ty = fy[j], tz = fz[j], tw = fw[j];
            float4 nr = nrm4v[j];
            float dot = fmaf(nax2[i].x, tx, fmaf(nay2[i].x, ty,
                         fmaf(naz2[i].x, tz, tw - BIAS)));
            float drec = fmaxf(a2 + dot, 0.0f);
            dr[i] = drec;
            bool cm = drec < 1e-4f;               // d_rec < 0.01^2
            if (cm) { lS_cmap += dpri; lN_cmap += 1.0f; }
            float ddot = (tx - ax) * nr.x + (ty - ay) * nr.y + (tz - az) * nr.z;
            if (ddot > 0.0f) lS_pen += drec;
        }
        float* dbase = drec_arr + (size_t)b * N1V + (size_t)chunk * 2048 + (size_t)tid * 8;
        *(float4*)dbase       = make_float4(dr[0], dr[1], dr[2], dr[3]);
        *(float4*)(dbase + 4) = make_float4(dr[4], dr[5], dr[6], dr[7]);
        atomicAdd(&s_red[0], lS_cmap);
        atomicAdd(&s_red[1], lN_cmap);
        atomicAdd(&s_red[2], lS_pen);
        __syncthreads();
        if (tid < 8) {
            float v = 0.0f;
            if (tid == 3) v = s_red[0];
            if (tid == 4) v = s_red[1];
            if (tid == 7) v = s_red[2];
            part[(size_t)blk * 8 + tid] = v;
        }
        return;
    }

    if (blk < REC_BLOCKS + GT_BLOCKS) {
        // ============ GT ROLE (PPT=8, packed fp32) ============
        int r = blk - REC_BLOCKS;
        int b = r >> 2, chunk = r & 3;
        const float4* gt4v = ws4 + (size_t)b * BATCH_F4;
        STAGE_SOA(s_x, s_y, s_z, s_w, gt4v, NQ)
        if (tid == 0) s_red[0] = 0.0f;
        __syncthreads();

        const float* ob = obj + ((size_t)b * N1V + (size_t)chunk * 2048) * 3;
        const float4* ob4 = (const float4*)(ob + (size_t)tid * 24);
        float4 q0 = ob4[0], q1 = ob4[1], q2 = ob4[2], q3 = ob4[3], q4 = ob4[4], q5 = ob4[5];

        v2f nax2[PPT], nay2[PPT], naz2[PPT];
        float mgt[PPT];
        {
            float px[PPT], py[PPT], pz[PPT];
            px[0]=q0.x; py[0]=q0.y; pz[0]=q0.z;
            px[1]=q0.w; py[1]=q1.x; pz[1]=q1.y;
            px[2]=q1.z; py[2]=q1.w; pz[2]=q2.x;
            px[3]=q2.y; py[3]=q2.z; pz[3]=q2.w;
            px[4]=q3.x; py[4]=q3.y; pz[4]=q3.z;
            px[5]=q3.w; py[5]=q4.x; pz[5]=q4.y;
            px[6]=q4.z; py[6]=q4.w; pz[6]=q5.x;
            px[7]=q5.y; py[7]=q5.z; pz[7]=q5.w;
#pragma unroll
            for (int i = 0; i < PPT; ++i) {
                float ax = -2.0f * px[i], ay = -2.0f * py[i], az = -2.0f * pz[i];
                nax2[i] = (v2f){ax, ax}; nay2[i] = (v2f){ay, ay}; naz2[i] = (v2f){az, az};
                mgt[i] = 3.4e38f;
            }
        }
        for (int j = 0; j < NQ; ++j) {
            v4f x4 = s_x[j], y4 = s_y[j], z4 = s_z[j], w4 = s_w[j];
            v2f xa = LO2(x4), xb = HI2(x4), ya = LO2(y4), yb = HI2(y4);
            v2f za = LO2(z4), zb = HI2(z4), wa = LO2(w4), wb = HI2(w4);
#pragma unroll
            for (int i = 0; i < PPT; ++i) {
                v2f da = PKFMA(nax2[i], xa, PKFMA(nay2[i], ya, PKFMA(naz2[i], za, wa)));
                v2f db = PKFMA(nax2[i], xb, PKFMA(nay2[i], yb, PKFMA(naz2[i], zb, wb)));
                mgt[i] = fminf(fminf(mgt[i], fminf(da.x, da.y)), fminf(db.x, db.y));
            }
        }
        float lN_gt = 0.0f;
        unsigned int gbits = 0;
#pragma unroll
        for (int i = 0; i < PPT; ++i) {
            float ax = -0.5f * nax2[i].x, ay = -0.5f * nay2[i].x, az = -0.5f * naz2[i].x;
            float a2 = ax*ax + ay*ay + az*az;
            float dgt = fmaxf(a2 + mgt[i], 0.0f);
            bool gc = sqrtf(dgt) < 0.005f;
            if (gc) { lN_gt += 1.0f; gbits |= (1u << i); }
        }
        gc_arr[(size_t)r * 256 + tid] = gbits;
        atomicAdd(&s_red[0], lN_gt);
        __syncthreads();
        if (tid < 8) {
            float v = (tid == 5) ? s_red[0] : 0.0f;
            part[(size_t)blk * 8 + tid] = v;
        }
        return;
    }

    // ============ CHAMFER ROLE (4 sources/thread, packed fp32) ============
    {
        int c   = blk - (REC_BLOCKS + GT_BLOCKS);
        int b   = c >> 1;
        int dir = c & 1;           // 0: rec->gt, 1: gt->rec
        const float4* base = ws4 + (size_t)b * BATCH_F4;
        const float4* srcv = dir ? base : (base + NVP);   // gt4 : rec4
        const float4* tgtv = dir ? (base + NVP) : base;   // rec4 : gt4
        STAGE_SOA(s_x, s_y, s_z, s_w, tgtv, NQ)
        if (tid == 0) s_red[0] = 0.0f;
        __syncthreads();

        const int CPT = 4;               // 256*4 = 1024 >= 778 sources
        v2f nax2[CPT], nay2[CPT], naz2[CPT];
        float a2[CPT], m[CPT];
        bool valid[CPT];
#pragma unroll
        for (int k = 0; k < CPT; ++k) {
            int p = tid + 256 * k;
            valid[k] = (p < NV);
            float4 s = srcv[valid[k] ? p : 0];
            float ax = -2.0f * s.x, ay = -2.0f * s.y, az = -2.0f * s.z;
            nax2[k] = (v2f){ax, ax}; nay2[k] = (v2f){ay, ay}; naz2[k] = (v2f){az, az};
            a2[k] = s.w;                  // one of src/tgt carries +BIAS
            m[k] = 3.4e38f;
        }
        for (int j = 0; j < NQ; ++j) {
            v4f x4 = s_x[j], y4 = s_y[j], z4 = s_z[j], w4 = s_w[j];
            v2f xa = LO2(x4), xb = HI2(x4), ya = LO2(y4), yb = HI2(y4);
            v2f za = LO2(z4), zb = HI2(z4), wa = LO2(w4), wb = HI2(w4);
#pragma unroll
            for (int k = 0; k < CPT; ++k) {
                v2f da = PKFMA(nax2[k], xa, PKFMA(nay2[k], ya, PKFMA(naz2[k], za, wa)));
                v2f db = PKFMA(nax2[k], xb, PKFMA(nay2[k], yb, PKFMA(naz2[k], zb, wb)));
                m[k] = fminf(fminf(m[k], fminf(da.x, da.y)), fminf(db.x, db.y));
            }
        }
        float local = 0.0f;
#pragma unroll
        for (int k = 0; k < CPT; ++k)
            if (valid[k]) local += fmaxf(a2[k] + m[k] - BIAS, 0.0f);
        atomicAdd(&s_red[0], local);
        __syncthreads();
        if (tid < 8) {
            float v = (tid == 2) ? s_red[0] : 0.0f;
            part[(size_t)blk * 8 + tid] = v;
        }
    }
}

// ---------------- Combine: consistency count = sum(rc & gc) ----------------
__global__ __launch_bounds__(256) void k_combine(const float* __restrict__ drec_arr,
                                                 const unsigned int* __restrict__ gc_arr,
                                                 float* __restrict__ part) {
    int blk = blockIdx.x, tid = threadIdx.x;
    __shared__ float s_red;
    if (tid == 0) s_red = 0.0f;
    __syncthreads();
    const float* dbase = drec_arr + (size_t)blk * 2048 + (size_t)tid * 8;
    float4 da = *(const float4*)dbase;
    float4 db = *(const float4*)(dbase + 4);
    unsigned int g = gc_arr[(size_t)blk * 256 + tid];
    float cnt = 0.0f;
    if ((sqrtf(da.x) < 0.005f) && (g & 0x01u)) cnt += 1.0f;
    if ((sqrtf(da.y) < 0.005f) && (g & 0x02u)) cnt += 1.0f;
    if ((sqrtf(da.z) < 0.005f) && (g & 0x04u)) cnt += 1.0f;
    if ((sqrtf(da.w) < 0.005f) && (g & 0x08u)) cnt += 1.0f;
    if ((sqrtf(db.x) < 0.005f) && (g & 0x10u)) cnt += 1.0f;
    if ((sqrtf(db.y) < 0.005f) && (g & 0x20u)) cnt += 1.0f;
    if ((sqrtf(db.z) < 0.005f) && (g & 0x40u)) cnt += 1.0f;
    if ((sqrtf(db.w) < 0.005f) && (g & 0x80u)) cnt += 1.0f;
    atomicAdd(&s_red, cnt);
    __syncthreads();
    if (tid < 8) {
        float v = (tid == 6) ? s_red : 0.0f;
        part[(size_t)(NROLE_BLOCKS + blk) * 8 + tid] = v;
    }
}

// ---------------- Finalize: param/KLD reductions + partial row-sum + loss ----
__global__ __launch_bounds__(256) void k_final(const float* __restrict__ part,
                                               const float* __restrict__ mean,
                                               const float* __restrict__ log_var,
                                               const float* __restrict__ rp,
                                               const float* __restrict__ xp,
                                               float* __restrict__ out) {
    int tid = threadIdx.x;
    __shared__ float red[8];
    if (tid < 8) red[tid] = 0.0f;
    __syncthreads();
    float l2=0, l3=0, l4=0, l5=0, l6=0, l7=0;
    for (int r = tid; r < TOT_ROWS; r += 256) {
        const float* row = part + (size_t)r * 8;
        l2 += row[2]; l3 += row[3]; l4 += row[4];
        l5 += row[5]; l6 += row[6]; l7 += row[7];
    }
    float s_param = 0.0f, s_kld = 0.0f;
    for (int i = tid; i < NB * NPAR; i += 256) {
        float d = rp[i] - xp[i];
        s_param += d * d;
    }
    for (int i = tid; i < NB * NZ; i += 256) {
        float m = mean[i], lv = log_var[i];
        s_kld += 1.0f + lv - m * m - expf(lv);
    }
    atomicAdd(&red[0], s_param);
    atomicAdd(&red[1], s_kld);
    atomicAdd(&red[2], l2);
    atomicAdd(&red[3], l3);
    atomicAdd(&red[4], l4);
    atomicAdd(&red[5], l5);
    atomicAdd(&red[6], l6);
    atomicAdd(&red[7], l7);
    __syncthreads();
    if (tid == 0) {
        const float fB = 64.0f;
        float param_loss  = red[0] / fB;
        float KLD         = -0.5f * red[1] / fB * 10.0f;
        float recon_loss  = red[2] / fB;
        float cmap_loss   = 3000.0f * red[3] / (fB * red[4]);
        float consistency = -5.0f * red[6] / (red[5] + 0.0001f);
        float penetr      = 100.0f * red[7] / fB;
        out[0] = (recon_loss + KLD) + 0.1f * param_loss + 1000.0f * cmap_loss
               + 10.0f * consistency + 10.0f * penetr;
    }
}

extern "C" void kernel_launch(void* const* d_in, const int* in_sizes, int n_in,
                              void* d_out, int out_size, void* d_ws, size_t ws_size,
                              hipStream_t stream) {
    (void)in_sizes; (void)n_in; (void)out_size; (void)ws_size;
    const float* obj     = (const float*)d_in[0];
    const float* recon   = (const float*)d_in[1];
    const float* gt      = (const float*)d_in[2];
    const float* mean    = (const float*)d_in[3];
    const float* log_var = (const float*)d_in[4];
    const float* rp      = (const float*)d_in[5];
    const float* xp      = (const float*)d_in[6];
    const int*   faces   = (const int*)d_in[7];
    float4* ws4 = (float4*)d_ws;
    float* part = (float*)d_ws + PART_OFF;
    float* drec = (float*)d_ws + DREC_OFF;
    unsigned int* gc = (unsigned int*)((float*)d_ws + GC_OFF);
    float* out  = (float*)d_out;

    k_prep   <<<NB,           256, 0, stream>>>(recon, gt, faces, ws4);
    k_fused  <<<NROLE_BLOCKS, 256, 0, stream>>>(obj, ws4, part, drec, gc);
    k_combine<<<CMB_BLOCKS,   256, 0, stream>>>(drec, gc, part);
    k_final  <<<1,            256, 0, stream>>>(part, mean, log_var, rp, xp, out);
}